// Round 5
// baseline (230.699 us; speedup 1.0000x reference)
//
#include <hip/hip_runtime.h>

// NMS3D (4,4,32,256,256) fp32, strict 26-neighbor max.
// R11: R9 geometry (the champion: 36 KiB tile, 4 blocks/CU, 8192 independent
// blocks, stage -> one sync -> compute) + two orthogonal, sync-free changes:
//  (a) NORMAL stores instead of nontemporal: nt bypasses L2 -> 134 MB of
//      writes queue synchronously at HBM controllers; plain stores absorb
//      into L2 (32 MB) and drain async. Fill kernel (plain stores) = 6.7 TB/s
//      vs our ~3.5 effective.
//  (b) chunked XCD swizzle (T1, bijective: 8192 % 8 == 0): hc-adjacent blocks
//      share halo rows; default round-robin puts them on different XCDs
//      (halo fetched into 2-3 L2s, served via L3). Chunks of 1024 logical
//      blocks (= 2 full bc channels) per XCD -> halo reuse is same-L2.
// Geometry scan closed: 2/4/6 blocks/CU = 65/62/64 us -> TLP not binding;
// residual is store backpressure / cache locality (this round's test).
// Math verified absmax 0.0 in R6-R10: separable vertical max + lane shuffles.

typedef float v4f __attribute__((ext_vector_type(4)));

constexpr int W  = 256;
constexpr int H  = 256;
constexpr int D  = 32;
constexpr int SH = W;
constexpr int SD = W * H;
constexpr int KD = 4;                  // d outputs per block (1 per wave)
constexpr int HC = 4;                  // h rows per block
constexpr int BC = 16;                 // B*CH
constexpr int DG = D / KD;             // 8
constexpr int HG = H / HC;             // 64
constexpr int NPL = KD + 2;            // 6 staged planes
constexpr int NR  = HC + 2;            // 6 staged rows per plane
constexpr int TROWS = NPL * NR;        // 36 rows of W floats = 36 KiB
constexpr int NWG = BC * DG * HG;      // 8192 blocks
constexpr int NXCD = 8;
constexpr int CPX = NWG / NXCD;        // 1024 logical blocks per XCD chunk

__device__ __forceinline__ v4f vmax4(v4f a, v4f b) {
    return (v4f){fmaxf(a.x, b.x), fmaxf(a.y, b.y), fmaxf(a.z, b.z), fmaxf(a.w, b.w)};
}

__global__ __launch_bounds__(256, 4) void nms3d_kernel(const float* __restrict__ x,
                                                       float* __restrict__ out) {
    __shared__ float lds[TROWS * W];   // 36 KiB -> 4 blocks/CU

    // chunked XCD swizzle: hardware bid round-robins XCDs (bid&7 = XCD),
    // so logical ids l = (bid&7)*CPX + bid>>3 give each XCD one contiguous
    // chunk of 1024 logical blocks (= 2 full bc volumes). Bijective (8192%8==0).
    const int bid  = blockIdx.x;
    const int blk  = (bid & (NXCD - 1)) * CPX + (bid >> 3);

    const int wv   = threadIdx.x >> 6;   // 0..3
    const int lane = threadIdx.x & 63;
    const int hc   = blk & (HG - 1);            // fastest: h-neighbors share halo in L2
    const int dg   = (blk >> 6) & (DG - 1);
    const int bc   = blk >> 9;
    const int d0   = dg * KD;
    const int h0   = hc * HC;

    const float* vol = x + bc * (D * SD);

    // ---- stage 36 rows; wave wv stages flat rows t = wv*9 .. wv*9+8 ----
    #pragma unroll
    for (int u = 0; u < TROWS / 4; ++u) {       // 9 DMA instrs per wave
        const int t = wv * (TROWS / 4) + u;
        const int j = t / NR;
        const int r = t - j * NR;
        int p = d0 - 1 + j;  p = p < 0 ? 0 : (p > D - 1 ? D - 1 : p);
        int hh = h0 - 1 + r; hh = hh < 0 ? 0 : (hh > H - 1 ? H - 1 : hh);
        const float* gp = vol + p * SD + hh * SH + (lane << 2);
        // lane i's 16B land at ldsbase + 16*i -> exactly row-major row layout
        __builtin_amdgcn_global_load_lds(
            (const __attribute__((address_space(1))) unsigned int*)gp,
            (__attribute__((address_space(3))) unsigned int*)&lds[(j * NR + r) * W],
            16, 0, 0);
    }
    __syncthreads();   // drains vmcnt (DMA) then barrier — the block's only sync

    // ---- compute: wave wv handles output plane d = d0 + wv ----
    const int d = d0 + wv;
    const bool dv = (d > 0) && (d < D - 1);
    float* ovol = out + bc * (D * SD) + d * SD + (lane << 2);

    const float* Lm = lds + (wv * NR) * W + (lane << 2);        // plane d-1
    const float* L0 = lds + ((wv + 1) * NR) * W + (lane << 2);  // plane d
    const float* Lp = lds + ((wv + 2) * NR) * W + (lane << 2);  // plane d+1

    // rolling 3-row window per plane, slot = (row mod 3), fully unrolled
    v4f rm[3], r0[3], rp[3];
    rm[0] = *(const v4f*)(Lm + 0 * W); r0[0] = *(const v4f*)(L0 + 0 * W); rp[0] = *(const v4f*)(Lp + 0 * W);
    rm[1] = *(const v4f*)(Lm + 1 * W); r0[1] = *(const v4f*)(L0 + 1 * W); rp[1] = *(const v4f*)(Lp + 1 * W);

    #pragma unroll
    for (int i = 0; i < HC; ++i) {
        const int s0 = i % 3, s1 = (i + 1) % 3, s2 = (i + 2) % 3;
        rm[s2] = *(const v4f*)(Lm + (i + 2) * W);
        r0[s2] = *(const v4f*)(L0 + (i + 2) * W);
        rp[s2] = *(const v4f*)(Lp + (i + 2) * W);

        // separable: per-plane maxes over the 3 h-rows
        const v4f a3m = vmax4(vmax4(rm[s0], rm[s1]), rm[s2]);   // plane d-1, all rows
        const v4f a3p = vmax4(vmax4(rp[s0], rp[s1]), rp[s2]);   // plane d+1, all rows
        const v4f a20 = vmax4(r0[s0], r0[s2]);                  // plane d, h +- 1
        const v4f v8  = vmax4(vmax4(a3m, a3p), a20);            // 8 non-center rows
        const v4f c   = r0[s1];

        const float l8 = __shfl_up(v8.w, 1);     // lane0 garbage, masked
        const float r8 = __shfl_down(v8.x, 1);   // lane63 garbage, masked
        const float lc = __shfl_up(c.w, 1);
        const float rc = __shfl_down(c.x, 1);

        float n0 = fmaxf(fmaxf(l8,   v8.x), v8.y);
        float n1 = fmaxf(fmaxf(v8.x, v8.y), v8.z);
        float n2 = fmaxf(fmaxf(v8.y, v8.z), v8.w);
        float n3 = fmaxf(fmaxf(v8.z, v8.w), r8);
        n0 = fmaxf(n0, fmaxf(lc,  c.y));
        n1 = fmaxf(n1, fmaxf(c.x, c.z));
        n2 = fmaxf(n2, fmaxf(c.y, c.w));
        n3 = fmaxf(n3, fmaxf(c.z, rc));

        const int h = h0 + i;
        const bool hv = (h > 0) && (h < H - 1);   // wave-uniform
        const bool v  = hv && dv;
        v4f o;
        o.x = (v && lane > 0  && c.x > n0) ? c.x : 0.f;
        o.y = (v && c.y > n1) ? c.y : 0.f;
        o.z = (v && c.z > n2) ? c.z : 0.f;
        o.w = (v && lane < 63 && c.w > n3) ? c.w : 0.f;
        // NORMAL store (R11): land in L2, drain async. nt bypassed L2 and
        // exposed HBM-controller backpressure to the wave.
        *(v4f*)(ovol + h * SH) = o;
    }
}

extern "C" void kernel_launch(void* const* d_in, const int* in_sizes, int n_in,
                              void* d_out, int out_size, void* d_ws, size_t ws_size,
                              hipStream_t stream) {
    const float* x = (const float*)d_in[0];
    float* out = (float*)d_out;
    // blocks = BC * DG * HG = 16*8*64 = 8192, 256 threads each, 4 blocks/CU
    nms3d_kernel<<<NWG, 256, 0, stream>>>(x, out);
}